// Round 2
// baseline (219.919 us; speedup 1.0000x reference)
//
#include <hip/hip_runtime.h>
#include <hip/hip_bf16.h>
#include <cstdint>

#define NEG_BIG (-1.0e9f)

typedef __attribute__((ext_vector_type(8))) short short8_t;
typedef __attribute__((ext_vector_type(4))) float f32x4;

__device__ __forceinline__ short f2bf(float x) {
  union { float f; unsigned u; } v; v.f = x;
  unsigned r = v.u + 0x7fffu + ((v.u >> 16) & 1u);
  return (short)(r >> 16);
}
__device__ __forceinline__ float sigmoidf_(float x) { return 1.0f / (1.0f + __expf(-x)); }

// ---------------- K0: pack A1 = [emb[prev] | h0] as bf16, rows of 1536 ----------------
__global__ void k_pack_a1(const int* __restrict__ prev, const float* __restrict__ emb,
                          const float* __restrict__ h0, short* __restrict__ A1) {
  int t = blockIdx.x * 256 + threadIdx.x;
  if (t >= 128 * 1536) return;
  int b = t / 1536, k = t - b * 1536;
  float v = (k < 512) ? emb[(size_t)prev[b] * 512 + k] : h0[b * 1024 + (k - 512)];
  A1[t] = f2bf(v);
}

// ---------------- generic M=128 bf16-MFMA GEMM: C = A(bf16) @ W(f32)^T ----------------
// WN=1: BN=16, 4 waves split M (2 m-reps each). WN=4: BN=64, waves split N (8 m-reps).
// W is [N][K] f32 row-major, converted to bf16 in-flight. K window may span two
// matrices: k < Ka -> Wa (ld ldwa), else Wb (ld ldwb, k-Ka).
// EPI 0: outF[m*ldo+n] = acc + bias0[n] (+bias1[n]).  EPI 1: outB = bf16(tanh(acc)).
template <int WN, int EPI>
__launch_bounds__(256, 2)
__global__ void k_gemm(const short* __restrict__ A, int lda,
                       const float* __restrict__ Wa, int ldwa, int Ka,
                       const float* __restrict__ Wb, int ldwb,
                       int Ktot,
                       const float* __restrict__ bias0, const float* __restrict__ bias1,
                       float* __restrict__ outF, short* __restrict__ outB, int ldo) {
  constexpr int BN = WN * 16;
  constexpr int MREP = 2 * WN;
  __shared__ __align__(16) short lA[128 * 64];
  __shared__ __align__(16) short lW[BN * 64];
  const int tid = threadIdx.x;
  const int wid = tid >> 6;
  const int l = tid & 63;
  const int nblk = blockIdx.x;
  const int l15 = l & 15;
  const int khalf = l >> 4;                         // 0..3
  const int m_wave = (WN == 1) ? wid * 32 : 0;
  const int nb_local = (WN == 4) ? wid * 16 : 0;

  f32x4 acc[MREP];
#pragma unroll
  for (int r = 0; r < MREP; ++r) acc[r] = (f32x4){0.f, 0.f, 0.f, 0.f};

  const int arow = tid >> 1;                        // 0..127
  const int ahalf = tid & 1;
  const int aswz = (arow & 7) << 4;

  for (int k0 = 0; k0 < Ktot; k0 += 64) {
    // stage A tile [128][64] bf16 (already bf16 in ws), XOR-swizzled rows.
    // Each thread covers 32 elements (64 bytes) = 4x short8.
    {
      const short8_t* src = (const short8_t*)(A + (size_t)arow * lda + k0 + ahalf * 32);
      char* drow = (char*)lA + arow * 128;
#pragma unroll
      for (int q = 0; q < 4; ++q) {
        short8_t a = src[q];
        *(short8_t*)(drow + ((ahalf * 64 + q * 16) ^ aswz)) = a;
      }
    }
    // stage W tile [BN][64]: f32 load -> bf16 cvt -> swizzled ds_write
#pragma unroll
    for (int base = 0; base < BN * 64; base += 1024) {
      int idx = base + tid * 4;
      int n = idx >> 6;
      int kq = idx & 63;
      int kg = k0 + kq;
      const float* srcp = (kg < Ka)
                              ? (Wa + (size_t)(nblk * BN + n) * ldwa + kg)
                              : (Wb + (size_t)(nblk * BN + n) * ldwb + (kg - Ka));
      float4 v = *(const float4*)srcp;
      short4 h4;
      h4.x = f2bf(v.x); h4.y = f2bf(v.y); h4.z = f2bf(v.z); h4.w = f2bf(v.w);
      *(short4*)((char*)lW + n * 128 + ((kq * 2) ^ ((n & 7) << 4))) = h4;
    }
    __syncthreads();
#pragma unroll
    for (int ks = 0; ks < 2; ++ks) {
      const int ubyte = ks * 64 + khalf * 16;       // 16B unit within row
      const int nrow = nb_local + l15;
      short8_t bfrag = *(const short8_t*)((char*)lW + nrow * 128 + (ubyte ^ ((nrow & 7) << 4)));
#pragma unroll
      for (int r = 0; r < MREP; ++r) {
        const int mrow = m_wave + r * 16 + l15;
        short8_t afrag = *(const short8_t*)((char*)lA + mrow * 128 + (ubyte ^ ((mrow & 7) << 4)));
        acc[r] = __builtin_amdgcn_mfma_f32_16x16x32_bf16(afrag, bfrag, acc[r], 0, 0, 0);
      }
    }
    __syncthreads();
  }

  const int n = nblk * BN + nb_local + l15;
  float bias = 0.f;
  if (bias0) bias = bias0[n];
  if (bias1) bias += bias1[n];
#pragma unroll
  for (int r = 0; r < MREP; ++r) {
    int mb = m_wave + r * 16 + khalf * 4;
#pragma unroll
    for (int e = 0; e < 4; ++e) {
      float v = acc[r][e] + bias;
      if (EPI == 1) {
        outB[(size_t)(mb + e) * ldo + n] = f2bf(tanhf(v));
      } else {
        outF[(size_t)(mb + e) * ldo + n] = v;
      }
    }
  }
}

// ---------------- K2: LSTM elementwise ----------------
__global__ void k_lstm(const float* __restrict__ gates, const float* __restrict__ c0,
                       float* __restrict__ h1_out, float* __restrict__ c1_out,
                       short* __restrict__ A3) {
  int t = blockIdx.x * 256 + threadIdx.x;  // 131072
  int b = t >> 10, h = t & 1023;
  const float* g = gates + (size_t)b * 4096;
  float ig = sigmoidf_(g[h]);
  float fg = sigmoidf_(g[1024 + h]);
  float gg = tanhf(g[2048 + h]);
  float og = sigmoidf_(g[3072 + h]);
  float c1 = fg * c0[t] + ig * gg;
  float h1 = og * tanhf(c1);
  c1_out[t] = c1;
  h1_out[t] = h1;
  A3[(size_t)b * 2048 + 1024 + h] = f2bf(h1);  // second half of concat row
}

// ---------------- K4: flash attention pass (ctx read ONCE) ----------------
// grid 512: b = bid>>2, chunk = bid&3 (128 s each); each wave owns 32 s.
// Emits raw scores (for exact alpha) + per-wave online-softmax partials (m, l, w[1024]).
__global__ void k_attn(const float* __restrict__ ctx, const float* __restrict__ target,
                       const unsigned char* __restrict__ mask,
                       float* __restrict__ scores, float* __restrict__ part) {
  int b = blockIdx.x >> 2, chunk = blockIdx.x & 3;
  int wid = threadIdx.x >> 6, l = threadIdx.x & 63;
  const float* tg = target + (size_t)b * 1024;
  float4 t4[4], w4[4];
#pragma unroll
  for (int j = 0; j < 4; ++j) {
    t4[j] = *(const float4*)(tg + j * 256 + l * 4);
    w4[j].x = 0.f; w4[j].y = 0.f; w4[j].z = 0.f; w4[j].w = 0.f;
  }
  float m = -INFINITY, lsum = 0.f;
  const int s0 = chunk * 128 + wid * 32;
  const float* cb = ctx + ((size_t)b * 512 + s0) * 1024;
  const unsigned char* mk = mask + (size_t)b * 512 + s0;
  for (int ss = 0; ss < 32; ++ss) {
    const float* crow = cb + (size_t)ss * 1024;
    float4 c4[4];
    float p = 0.f;
#pragma unroll
    for (int j = 0; j < 4; ++j) {
      c4[j] = *(const float4*)(crow + j * 256 + l * 4);
      p += c4[j].x * t4[j].x + c4[j].y * t4[j].y + c4[j].z * t4[j].z + c4[j].w * t4[j].w;
    }
#pragma unroll
    for (int off = 32; off > 0; off >>= 1) p += __shfl_xor(p, off);
    if (mk[ss]) p = NEG_BIG;
    if (l == 0) scores[(size_t)b * 512 + s0 + ss] = p;
    float mn = fmaxf(m, p);
    float scale = __expf(m - mn);
    float e = __expf(p - mn);
    lsum = lsum * scale + e;
#pragma unroll
    for (int j = 0; j < 4; ++j) {
      w4[j].x = w4[j].x * scale + e * c4[j].x;
      w4[j].y = w4[j].y * scale + e * c4[j].y;
      w4[j].z = w4[j].z * scale + e * c4[j].z;
      w4[j].w = w4[j].w * scale + e * c4[j].w;
    }
    m = mn;
  }
  float* pp = part + ((size_t)b * 16 + (chunk * 4 + wid)) * 1028;
#pragma unroll
  for (int j = 0; j < 4; ++j) *(float4*)(pp + j * 256 + l * 4) = w4[j];
  if (l == 0) { pp[1024] = m; pp[1025] = lsum; }
}

// ---------------- K5: exact softmax over stored scores -> alpha ----------------
__global__ void k_alpha(const float* __restrict__ scores, float* __restrict__ alpha) {
  __shared__ float red[256];
  int b = blockIdx.x, t = threadIdx.x;
  float s0 = scores[(size_t)b * 512 + t];
  float s1 = scores[(size_t)b * 512 + 256 + t];
  red[t] = fmaxf(s0, s1);
  __syncthreads();
  for (int o = 128; o > 0; o >>= 1) {
    if (t < o) red[t] = fmaxf(red[t], red[t + o]);
    __syncthreads();
  }
  float M = red[0];
  __syncthreads();
  float e0 = __expf(s0 - M), e1 = __expf(s1 - M);
  red[t] = e0 + e1;
  __syncthreads();
  for (int o = 128; o > 0; o >>= 1) {
    if (t < o) red[t] += red[t + o];
    __syncthreads();
  }
  float inv = 1.0f / red[0];
  alpha[(size_t)b * 512 + t] = e0 * inv;
  alpha[(size_t)b * 512 + 256 + t] = e1 * inv;
}

// ---------------- K6: combine flash partials -> weighted (bf16 into A3 first half) ----
__global__ void k_combine(const float* __restrict__ part, short* __restrict__ A3) {
  __shared__ float sm[16], sl[16];
  int b = blockIdx.x, t = threadIdx.x;
  if (t < 16) {
    sm[t] = part[((size_t)b * 16 + t) * 1028 + 1024];
    sl[t] = part[((size_t)b * 16 + t) * 1028 + 1025];
  }
  __syncthreads();
  float M = -INFINITY;
#pragma unroll
  for (int i = 0; i < 16; ++i) M = fmaxf(M, sm[i]);
  float scl[16];
  float L = 0.f;
#pragma unroll
  for (int i = 0; i < 16; ++i) {
    scl[i] = __expf(sm[i] - M);
    L += sl[i] * scl[i];
  }
  float inv = 1.0f / L;
  int h = t * 4;
  float ax = 0.f, ay = 0.f, az = 0.f, aw = 0.f;
#pragma unroll
  for (int i = 0; i < 16; ++i) {
    const float4 w = *(const float4*)(part + ((size_t)b * 16 + i) * 1028 + h);
    ax += scl[i] * w.x; ay += scl[i] * w.y; az += scl[i] * w.z; aw += scl[i] * w.w;
  }
  short4 o4;
  o4.x = f2bf(ax * inv); o4.y = f2bf(ay * inv); o4.z = f2bf(az * inv); o4.w = f2bf(aw * inv);
  *(short4*)(A3 + (size_t)b * 2048 + h) = o4;
}

extern "C" void kernel_launch(void* const* d_in, const int* in_sizes, int n_in,
                              void* d_out, int out_size, void* d_ws, size_t ws_size,
                              hipStream_t stream) {
  const int* prev = (const int*)d_in[0];
  const float* h0 = (const float*)d_in[1];
  const float* c0 = (const float*)d_in[2];
  const float* ctx = (const float*)d_in[3];
  const unsigned char* mask = (const unsigned char*)d_in[4];
  const float* emb = (const float*)d_in[5];
  const float* W_ih = (const float*)d_in[6];
  const float* W_hh = (const float*)d_in[7];
  const float* b_ih = (const float*)d_in[8];
  const float* b_hh = (const float*)d_in[9];
  const float* W_in = (const float*)d_in[10];
  const float* W_out = (const float*)d_in[11];
  const float* W_dec = (const float*)d_in[12];
  const float* b_dec = (const float*)d_in[13];

  float* out_h1 = (float*)d_out;            // 128*1024
  float* out_c1 = out_h1 + 128 * 1024;      // 128*1024
  float* out_alpha = out_c1 + 128 * 1024;   // 128*512
  float* out_logit = out_alpha + 128 * 512; // 128*32000

  char* ws = (char*)d_ws;
  short* A1 = (short*)(ws + 0x000000);      // 128x1536 bf16 (384KB)
  float* gates = (float*)(ws + 0x060000);   // 128x4096 f32  (2MB)
  short* A3 = (short*)(ws + 0x260000);      // 128x2048 bf16 [weighted | h1] (512KB)
  float* target = (float*)(ws + 0x2E0000);  // 128x1024 f32  (512KB)
  float* scores = (float*)(ws + 0x360000);  // 128x512 f32   (256KB)
  float* part = (float*)(ws + 0x3A0000);    // 128x16x1028 f32 (8.03MB)
  short* htilde = (short*)(ws + 0xBA8000);  // 128x1024 bf16 (256KB)

  // 1) pack gather+h0 operand
  k_pack_a1<<<768, 256, 0, stream>>>(prev, emb, h0, A1);
  // 2) gates = [emb|h0] @ [W_ih|W_hh]^T + b_ih + b_hh   (N=4096, K=1536)
  k_gemm<1, 0><<<256, 256, 0, stream>>>(A1, 1536, W_ih, 512, 512, W_hh, 1024, 1536,
                                        b_ih, b_hh, gates, nullptr, 4096);
  // 3) LSTM cell -> h_1, c_1 (+ bf16 h1 into A3 second half)
  k_lstm<<<512, 256, 0, stream>>>(gates, c0, out_h1, out_c1, A3);
  // 4) target = h1 @ W_in^T (N=1024, K=1024)
  k_gemm<1, 0><<<64, 256, 0, stream>>>(A3 + 1024, 2048, W_in, 1024, 1024, W_in, 1024, 1024,
                                       nullptr, nullptr, target, nullptr, 1024);
  // 5) flash attention over ctx (read once): scores + online partials
  k_attn<<<512, 256, 0, stream>>>(ctx, target, mask, scores, part);
  // 6) exact alpha from raw scores
  k_alpha<<<128, 256, 0, stream>>>(scores, out_alpha);
  // 7) combine partials -> weighted (bf16 into A3 first half)
  k_combine<<<128, 256, 0, stream>>>(part, A3);
  // 8) h_tilde = tanh([weighted|h1] @ W_out^T) (N=1024, K=2048), bf16 out
  k_gemm<1, 1><<<64, 256, 0, stream>>>(A3, 2048, W_out, 2048, 2048, W_out, 2048, 2048,
                                       nullptr, nullptr, nullptr, htilde, 1024);
  // 9) logit = h_tilde @ W_dec^T + b_dec (N=32000, K=1024)
  k_gemm<4, 0><<<500, 256, 0, stream>>>(htilde, 1024, W_dec, 1024, 1024, W_dec, 1024, 1024,
                                        b_dec, nullptr, out_logit, nullptr, 32000);
}